// Round 1
// baseline (50.551 us; speedup 1.0000x reference)
//
#include <hip/hip_runtime.h>

// IFNode multi-step forward, hard reset.
// x: (T=16, N=32, F=65536) f32. out: spikes, same shape/dtype.
// Per (n,f): v=0; for t: h=v+x[t]; spike=(h>=1); v = spike?0:h; out[t]=spike.
// Sequential only in T (register state); fully parallel and coalesced in N*F.

#define T_STEPS 16

__global__ __launch_bounds__(256) void ifnode_kernel(
    const float4* __restrict__ x4, float4* __restrict__ o4, int nf4) {
    int idx = blockIdx.x * blockDim.x + threadIdx.x;
    if (idx >= nf4) return;

    float4 v = make_float4(0.f, 0.f, 0.f, 0.f);

#pragma unroll
    for (int t = 0; t < T_STEPS; ++t) {
        float4 xv = x4[(size_t)t * nf4 + idx];
        float4 s;

        float h;
        h = v.x + xv.x; s.x = (h >= 1.0f) ? 1.0f : 0.0f; v.x = (h >= 1.0f) ? 0.0f : h;
        h = v.y + xv.y; s.y = (h >= 1.0f) ? 1.0f : 0.0f; v.y = (h >= 1.0f) ? 0.0f : h;
        h = v.z + xv.z; s.z = (h >= 1.0f) ? 1.0f : 0.0f; v.z = (h >= 1.0f) ? 0.0f : h;
        h = v.w + xv.w; s.w = (h >= 1.0f) ? 1.0f : 0.0f; v.w = (h >= 1.0f) ? 0.0f : h;

        o4[(size_t)t * nf4 + idx] = s;
    }
}

extern "C" void kernel_launch(void* const* d_in, const int* in_sizes, int n_in,
                              void* d_out, int out_size, void* d_ws, size_t ws_size,
                              hipStream_t stream) {
    const float* x = (const float*)d_in[0];
    float* out = (float*)d_out;

    // in_sizes[0] = T*N*F; per-step element count:
    int nf = in_sizes[0] / T_STEPS;   // 32*65536 = 2097152
    int nf4 = nf / 4;                 // 524288 float4 elements per step

    int block = 256;
    int grid = (nf4 + block - 1) / block;  // 2048

    ifnode_kernel<<<grid, block, 0, stream>>>(
        (const float4*)x, (float4*)out, nf4);
}

// Round 2
// 45.576 us; speedup vs baseline: 1.1091x; 1.1091x over previous
//
#include <hip/hip_runtime.h>

// IFNode multi-step forward, hard reset.
// x: (T=16, N=32, F=65536) f32. out: spikes, same shape/dtype.
// Per (n,f): v=0; for t: h=v+x[t]; spike=(h>=1); v = spike?0:h; out[t]=spike.
// Sequential only in T (register state); fully parallel + coalesced in N*F.
//
// Round-1 insight: input (134MB) is L3-resident across replays, but normal
// stores allocate in L3 and evict it (FETCH_SIZE ~65MB). Nontemporal stores
// keep the output stream out of the cache -> input stays fully L3-resident,
// HBM traffic drops to ~write-only (~134MB).

#define T_STEPS 16

typedef float v4f __attribute__((ext_vector_type(4)));

__global__ __launch_bounds__(256) void ifnode_kernel(
    const v4f* __restrict__ x4, v4f* __restrict__ o4, int nf4) {
    int idx = blockIdx.x * blockDim.x + threadIdx.x;
    if (idx >= nf4) return;

    v4f v = {0.f, 0.f, 0.f, 0.f};

#pragma unroll
    for (int t = 0; t < T_STEPS; ++t) {
        v4f xv = x4[(size_t)t * nf4 + idx];
        v4f s;

        float h;
        h = v.x + xv.x; s.x = (h >= 1.0f) ? 1.0f : 0.0f; v.x = (h >= 1.0f) ? 0.0f : h;
        h = v.y + xv.y; s.y = (h >= 1.0f) ? 1.0f : 0.0f; v.y = (h >= 1.0f) ? 0.0f : h;
        h = v.z + xv.z; s.z = (h >= 1.0f) ? 1.0f : 0.0f; v.z = (h >= 1.0f) ? 0.0f : h;
        h = v.w + xv.w; s.w = (h >= 1.0f) ? 1.0f : 0.0f; v.w = (h >= 1.0f) ? 0.0f : h;

        __builtin_nontemporal_store(s, &o4[(size_t)t * nf4 + idx]);
    }
}

extern "C" void kernel_launch(void* const* d_in, const int* in_sizes, int n_in,
                              void* d_out, int out_size, void* d_ws, size_t ws_size,
                              hipStream_t stream) {
    const float* x = (const float*)d_in[0];
    float* out = (float*)d_out;

    int nf = in_sizes[0] / T_STEPS;   // 32*65536 = 2097152
    int nf4 = nf / 4;                 // 524288 v4f elements per step

    int block = 256;
    int grid = (nf4 + block - 1) / block;  // 2048

    ifnode_kernel<<<grid, block, 0, stream>>>(
        (const v4f*)x, (v4f*)out, nf4);
}